// Round 2
// baseline (840.481 us; speedup 1.0000x reference)
//
#include <hip/hip_runtime.h>
#include <stdint.h>

typedef __attribute__((ext_vector_type(8))) short short8;
typedef __attribute__((ext_vector_type(4))) float f4;

#define MFMA16(a, b, c) __builtin_amdgcn_mfma_f32_16x16x32_bf16(a, b, c, 0, 0, 0)

// ---------------- workspace layout (bytes) ----------------
#define NWCAT (384 * 512)
#define NW1B (512 * 128)
#define NW2B (64 * 128)
#define OFF_WCAT_HI 0
#define OFF_WCAT_LO (NWCAT * 2)
#define OFF_W1B_HI (NWCAT * 4)
#define OFF_W1B_LO (OFF_W1B_HI + NW1B * 2)
#define OFF_W2B_HI (OFF_W1B_HI + NW1B * 4)
#define OFF_W2B_LO (OFF_W2B_HI + NW2B * 2)
#define OFF_BIAS (OFF_W2B_HI + NW2B * 4) // 960 floats: b1a|b2a|bb1|bb2a|b1b|b2b
#define PREP_TOT (NWCAT + NW1B + NW2B + 960)

// ---------------- LDS layout (bytes) ----------------
#define L_HT 0       // float [64][260]  h1|h2 tile (fp32, +4 pad)
#define L_BIAS 66560 // ushort [64][132] b1vec(0..63)|hb2(64..127), bf16
#define L_WB 83456   // float [960] staged biases
#define L_QS 87296   // float [64][8] qs tile
#define L_BB 89344   // B buffer, 73728 B
#define SMEM_BYTES 163072

__device__ __forceinline__ void gll16(const void* g, void* l) {
  __builtin_amdgcn_global_load_lds((const __attribute__((address_space(1))) void*)g,
                                   (__attribute__((address_space(3))) void*)l, 16, 0, 0);
}

__device__ __forceinline__ unsigned short f2bf_rne(float v) {
  uint32_t u = __float_as_uint(v);
  u += 0x7FFFu + ((u >> 16) & 1u);
  return (unsigned short)(u >> 16);
}
__device__ __forceinline__ float bf2f(unsigned short x) {
  return __uint_as_float(((uint32_t)x) << 16);
}

// split fp32 -> bf16 hi (truncate) + bf16 lo (truncate of residual)
__device__ __forceinline__ void split1(float w, unsigned short& hi, unsigned short& lo) {
  uint32_t u = __float_as_uint(w);
  uint32_t uh = u & 0xFFFF0000u;
  hi = (unsigned short)(uh >> 16);
  float r = w - __uint_as_float(uh);
  lo = (unsigned short)(__float_as_uint(r) >> 16);
}

__device__ __forceinline__ void cvt_split8(f4 x0, f4 x1, short8& h, short8& l) {
#pragma unroll
  for (int i = 0; i < 4; i++) {
    {
      uint32_t u = __float_as_uint(x0[i]);
      uint32_t uh = u & 0xFFFF0000u;
      h[i] = (short)(uh >> 16);
      l[i] = (short)(__float_as_uint(x0[i] - __uint_as_float(uh)) >> 16);
    }
    {
      uint32_t u = __float_as_uint(x1[i]);
      uint32_t uh = u & 0xFFFF0000u;
      h[i + 4] = (short)(uh >> 16);
      l[i + 4] = (short)(__float_as_uint(x1[i] - __uint_as_float(uh)) >> 16);
    }
  }
}

// ================= prep: split+transpose weights into ws =================
__global__ void qmix_prep(const float* __restrict__ W1a, const float* __restrict__ b1a,
                          const float* __restrict__ W1b, const float* __restrict__ b1b,
                          const float* __restrict__ Wb1, const float* __restrict__ bb1,
                          const float* __restrict__ W2a, const float* __restrict__ b2a,
                          const float* __restrict__ W2b, const float* __restrict__ b2b,
                          const float* __restrict__ Wb2a, const float* __restrict__ bb2a,
                          uint8_t* __restrict__ ws) {
  int t = blockIdx.x * 256 + threadIdx.x;
  if (t < NWCAT) {
    // WcatT[n][k], n: 0..127 W1a | 128..255 W2a | 256..319 Wb1 | 320..383 Wb2a
    int n = t >> 9, k = t & 511;
    float w = (n < 128)   ? W1a[k * 128 + n]
              : (n < 256) ? W2a[k * 128 + (n - 128)]
              : (n < 320) ? Wb1[k * 64 + (n - 256)]
                          : Wb2a[k * 64 + (n - 320)];
    unsigned short hi, lo;
    split1(w, hi, lo);
    ((unsigned short*)(ws + OFF_WCAT_HI))[t] = hi;
    ((unsigned short*)(ws + OFF_WCAT_LO))[t] = lo;
  } else if (t < NWCAT + NW1B) {
    int i = t - NWCAT;
    int n = i >> 7, k = i & 127; // W1bT[n][k] = W1b[k][n]
    unsigned short hi, lo;
    split1(W1b[k * 512 + n], hi, lo);
    ((unsigned short*)(ws + OFF_W1B_HI))[i] = hi;
    ((unsigned short*)(ws + OFF_W1B_LO))[i] = lo;
  } else if (t < NWCAT + NW1B + NW2B) {
    int i = t - NWCAT - NW1B;
    int n = i >> 7, k = i & 127; // W2bT[n][k] = W2b[k][n]
    unsigned short hi, lo;
    split1(W2b[k * 64 + n], hi, lo);
    ((unsigned short*)(ws + OFF_W2B_HI))[i] = hi;
    ((unsigned short*)(ws + OFF_W2B_LO))[i] = lo;
  } else if (t < PREP_TOT) {
    int j = t - (NWCAT + NW1B + NW2B);
    float v = (j < 128)   ? b1a[j]
              : (j < 256) ? b2a[j - 128]
              : (j < 320) ? bb1[j - 256]
              : (j < 384) ? bb2a[j - 320]
              : (j < 896) ? b1b[j - 384]
                          : b2b[j - 896];
    ((float*)(ws + OFF_BIAS))[j] = v;
  }
}

// ================= main fused kernel =================
// block = 512 threads (8 waves), 64 batch rows per block
__global__ __launch_bounds__(512, 2) void qmix_main(const float* __restrict__ qs,
                                                    const float* __restrict__ s,
                                                    const float* __restrict__ Wb2b,
                                                    const float* __restrict__ bb2b,
                                                    const uint8_t* __restrict__ ws,
                                                    float* __restrict__ out) {
  const int tid = threadIdx.x;
  const int lane = tid & 63;
  const int wave = tid >> 6; // 0..7
  const int g = lane >> 4;   // 0..3
  const int m = lane & 15;   // 0..15
  const int blk = blockIdx.x;
  const int row0 = blk * 64;

  extern __shared__ char smem[];
  float* h_tile = (float*)(smem + L_HT);                     // [64][260]
  unsigned short* bias_t = (unsigned short*)(smem + L_BIAS); // [64][132]
  float* wb_bias = (float*)(smem + L_WB);
  float* qs_tile = (float*)(smem + L_QS);
  char* B_buf = smem + L_BB;

  const unsigned short* wcat_hi = (const unsigned short*)(ws + OFF_WCAT_HI);
  const unsigned short* wcat_lo = (const unsigned short*)(ws + OFF_WCAT_LO);
  const unsigned short* w1b_hi = (const unsigned short*)(ws + OFF_W1B_HI);
  const unsigned short* w1b_lo = (const unsigned short*)(ws + OFF_W1B_LO);
  const unsigned short* w2b_hi = (const unsigned short*)(ws + OFF_W2B_HI); // hi,lo contiguous

  // stage qs + biases (BUGFIX R1: block has 512 threads but 960 bias floats —
  // the old `if (tid < 960)` left wb_bias[512..959] (b1b[128:], all of b2b)
  // as LDS garbage. Strided loop covers all 960.)
  {
    int r = tid >> 3, a = tid & 7;
    qs_tile[tid] = qs[(row0 + r) * 8 + a];
#pragma unroll
    for (int j = tid; j < 960; j += 512) wb_bias[j] = ((const float*)(ws + OFF_BIAS))[j];
  }

  // ---------------- phase 1: C1 = s @ WcatT^T (64x384) ----------------
  const int rw = wave >> 2; // 0..1 (32 rows each)
  const int cw = wave & 3;  // 0..3 (96 cols each)
  f4 acc1[2][6];
#pragma unroll
  for (int a = 0; a < 2; a++)
#pragma unroll
    for (int b = 0; b < 6; b++) acc1[a][b] = (f4){0.f, 0.f, 0.f, 0.f};

  for (int ks = 0; ks < 16; ks++) {
// stage B chunk: [384 cols][32 k] hi + lo, 64B per col
#pragma unroll
    for (int i = 0; i < 6; i++) {
      int slot = wave * 6 + i;
      int plane = (slot >= 24) ? 1 : 0;
      int cb = (slot - plane * 24) * 16;
      const unsigned short* src =
          (plane ? wcat_lo : wcat_hi) + (cb + (lane >> 2)) * 512 + ks * 32 + (lane & 3) * 8;
      gll16(src, B_buf + plane * 24576 + cb * 64);
    }
    // A frags from global s (overlap with staging)
    short8 ah[2], al[2];
#pragma unroll
    for (int rf = 0; rf < 2; rf++) {
      const float* sp = s + (size_t)(row0 + rw * 32 + rf * 16 + m) * 512 + ks * 32 + g * 8;
      cvt_split8(*(const f4*)(sp), *(const f4*)(sp + 4), ah[rf], al[rf]);
    }
    __syncthreads();
#pragma unroll
    for (int cf = 0; cf < 6; cf++) {
      int colb = cw * 96 + cf * 16;
      const char* bp = B_buf + (colb + m) * 64 + g * 16;
      short8 bh = *(const short8*)(bp);
#pragma unroll
      for (int rf = 0; rf < 2; rf++) acc1[rf][cf] = MFMA16(ah[rf], bh, acc1[rf][cf]);
      if (colb < 256) { // split 3-pass only for h1/h2 columns
        short8 bl = *(const short8*)(bp + 24576);
#pragma unroll
        for (int rf = 0; rf < 2; rf++) {
          acc1[rf][cf] = MFMA16(ah[rf], bl, acc1[rf][cf]);
          acc1[rf][cf] = MFMA16(al[rf], bh, acc1[rf][cf]);
        }
      }
    }
    __syncthreads();
  }

// phase-1 epilogue: bias + activation, write h / bias tiles
#pragma unroll
  for (int rf = 0; rf < 2; rf++)
#pragma unroll
    for (int cf = 0; cf < 6; cf++) {
      int colb = cw * 96 + cf * 16;
      int col = colb + m;
      float bias = wb_bias[col];
#pragma unroll
      for (int r = 0; r < 4; r++) {
        int row = rw * 32 + rf * 16 + g * 4 + r;
        float v = acc1[rf][cf][r] + bias;
        if (colb < 256) {
          h_tile[row * 260 + col] = fmaxf(v, 0.f); // relu(h1|h2)
        } else {
          if (colb >= 320) v = fmaxf(v, 0.f); // relu(hb2); b1vec no act
          bias_t[row * 132 + (col - 256)] = f2bf_rne(v);
        }
      }
    }
  __syncthreads();

  // ---------------- phase 2a: w1 = abs(h1 @ W1b + b1b), fold q -> partials ----------------
  const int bw = wave >> 2; // 0..1 (32 rows)
  const int cwv = wave & 3; // 0..3 (128 w1-cols)
  f4 acc2[2][8];
#pragma unroll
  for (int a = 0; a < 2; a++)
#pragma unroll
    for (int b = 0; b < 8; b++) acc2[a][b] = (f4){0.f, 0.f, 0.f, 0.f};

  for (int ks = 0; ks < 4; ks++) {
#pragma unroll
    for (int i = 0; i < 8; i++) {
      int slot = wave * 8 + i;
      int plane = (slot >= 32) ? 1 : 0;
      int nb = (slot - plane * 32) * 16;
      const unsigned short* src =
          (plane ? w1b_lo : w1b_hi) + (nb + (lane >> 2)) * 128 + ks * 32 + (lane & 3) * 8;
      gll16(src, B_buf + plane * 32768 + nb * 64);
    }
    short8 ah[2], al[2];
#pragma unroll
    for (int rf = 0; rf < 2; rf++) {
      const f4* hp = (const f4*)(h_tile + (bw * 32 + rf * 16 + m) * 260 + ks * 32 + g * 8);
      cvt_split8(hp[0], hp[1], ah[rf], al[rf]);
    }
    __syncthreads();
#pragma unroll
    for (int cf = 0; cf < 8; cf++) {
      const char* bp = B_buf + (cwv * 128 + cf * 16 + m) * 64 + g * 16;
      short8 bh = *(const short8*)(bp);
      short8 bl = *(const short8*)(bp + 32768);
#pragma unroll
      for (int rf = 0; rf < 2; rf++) {
        acc2[rf][cf] = MFMA16(ah[rf], bh, acc2[rf][cf]);
        acc2[rf][cf] = MFMA16(ah[rf], bl, acc2[rf][cf]);
        acc2[rf][cf] = MFMA16(al[rf], bh, acc2[rf][cf]);
      }
    }
    __syncthreads();
  }

  // issue W2b' staging now (32KB linear) — overlaps the merge below
#pragma unroll
  for (int i = 0; i < 4; i++) {
    int slot = wave * 4 + i;
    gll16(w2b_hi + slot * 512 + lane * 8, B_buf + 34816 + slot * 1024);
  }

  // merge q·w1 partials: P0 = agents 0..3 (cwv 0,1), P1 = agents 4..7 (cwv 2,3)
  float* P0 = (float*)(B_buf);
  float* P1 = (float*)(B_buf + 17408);
  {
    float* P = (cwv >> 1) ? P1 : P0;
    auto w1val = [&](int rf, int cfi, int r) {
      int n = cwv * 128 + cfi * 16 + m;
      return fabsf(acc2[rf][cfi][r] + wb_bias[384 + n]);
    };
    if (!(cwv & 1)) {
#pragma unroll
      for (int rf = 0; rf < 2; rf++)
#pragma unroll
        for (int r = 0; r < 4; r++) {
          int row = bw * 32 + rf * 16 + g * 4 + r;
          float qa0 = qs_tile[row * 8 + 2 * cwv], qa1 = qs_tile[row * 8 + 2 * cwv + 1];
#pragma unroll
          for (int hi = 0; hi < 4; hi++)
            P[row * 68 + hi * 16 + m] = qa0 * w1val(rf, hi, r) + qa1 * w1val(rf, hi + 4, r);
        }
    }
    __syncthreads();
    if (cwv & 1) {
#pragma unroll
      for (int rf = 0; rf < 2; rf++)
#pragma unroll
        for (int r = 0; r < 4; r++) {
          int row = bw * 32 + rf * 16 + g * 4 + r;
          float qa0 = qs_tile[row * 8 + 2 * cwv], qa1 = qs_tile[row * 8 + 2 * cwv + 1];
#pragma unroll
          for (int hi = 0; hi < 4; hi++)
            P[row * 68 + hi * 16 + m] += qa0 * w1val(rf, hi, r) + qa1 * w1val(rf, hi + 4, r);
        }
    }
    __syncthreads();
  }

  // ---------------- phase 2b: w2 = abs(h2 @ W2b + b2b) ----------------
  const char* W2B = B_buf + 34816;
  f4 acc3[2];
#pragma unroll
  for (int a = 0; a < 2; a++) acc3[a] = (f4){0.f, 0.f, 0.f, 0.f};
  for (int ks = 0; ks < 4; ks++) {
    short8 ah[2], al[2];
#pragma unroll
    for (int rf = 0; rf < 2; rf++) {
      const f4* hp = (const f4*)(h_tile + (bw * 32 + rf * 16 + m) * 260 + 128 + ks * 32 + g * 8);
      cvt_split8(hp[0], hp[1], ah[rf], al[rf]);
    }
    const char* bp = W2B + (cwv * 16 + m) * 256 + ks * 64 + g * 16;
    short8 bh = *(const short8*)(bp);
    short8 bl = *(const short8*)(bp + 16384);
#pragma unroll
    for (int rf = 0; rf < 2; rf++) {
      acc3[rf] = MFMA16(ah[rf], bh, acc3[rf]);
      acc3[rf] = MFMA16(ah[rf], bl, acc3[rf]);
      acc3[rf] = MFMA16(al[rf], bh, acc3[rf]);
    }
  }
  __syncthreads(); // all waves done reading W2B
  float* w2t = (float*)(B_buf + 34816); // [64][68], overwrites W2B
#pragma unroll
  for (int rf = 0; rf < 2; rf++)
#pragma unroll
    for (int r = 0; r < 4; r++) {
      int row = bw * 32 + rf * 16 + g * 4 + r;
      int n = cwv * 16 + m;
      w2t[row * 68 + n] = fabsf(acc3[rf][r] + wb_bias[896 + n]);
    }
  __syncthreads();

  // ---------------- phase 3: hidden = elu(P + b1), out = hidden·w2 + hb2·Wb2b + bb2b ----------------
  {
    int b = tid >> 3, seg = tid & 7;
    float sum = 0.f;
#pragma unroll
    for (int jj = 0; jj < 8; jj++) {
      int j = seg * 8 + jj;
      float pre = P0[b * 68 + j] + P1[b * 68 + j] + bf2f(bias_t[b * 132 + j]);
      float hid = pre > 0.f ? pre : (expf(pre) - 1.f);
      sum += hid * w2t[b * 68 + j];
      sum += bf2f(bias_t[b * 132 + 64 + j]) * Wb2b[j]; // b2 partial
    }
    sum += __shfl_xor(sum, 1);
    sum += __shfl_xor(sum, 2);
    sum += __shfl_xor(sum, 4);
    if (seg == 0) out[row0 + b] = sum + bb2b[0];
  }
}

extern "C" void kernel_launch(void* const* d_in, const int* in_sizes, int n_in, void* d_out,
                              int out_size, void* d_ws, size_t ws_size, hipStream_t stream) {
  (void)in_sizes;
  (void)n_in;
  (void)out_size;
  (void)ws_size;
  const float* qs = (const float*)d_in[0];
  const float* s = (const float*)d_in[1];
  const float* W1a = (const float*)d_in[2];
  const float* b1a = (const float*)d_in[3];
  const float* W1b = (const float*)d_in[4];
  const float* b1b = (const float*)d_in[5];
  const float* Wb1 = (const float*)d_in[6];
  const float* bb1 = (const float*)d_in[7];
  const float* W2a = (const float*)d_in[8];
  const float* b2a = (const float*)d_in[9];
  const float* W2b = (const float*)d_in[10];
  const float* b2b = (const float*)d_in[11];
  const float* Wb2a = (const float*)d_in[12];
  const float* bb2a = (const float*)d_in[13];
  const float* Wb2b = (const float*)d_in[14];
  const float* bb2b = (const float*)d_in[15];
  float* out = (float*)d_out;
  uint8_t* ws = (uint8_t*)d_ws;

  hipFuncSetAttribute((const void*)qmix_main, hipFuncAttributeMaxDynamicSharedMemorySize,
                      SMEM_BYTES);

  qmix_prep<<<(PREP_TOT + 255) / 256, 256, 0, stream>>>(W1a, b1a, W1b, b1b, Wb1, bb1, W2a, b2a,
                                                        W2b, b2b, Wb2a, bb2a, ws);
  qmix_main<<<131072 / 64, 512, SMEM_BYTES, stream>>>(qs, s, Wb2b, bb2b, ws, out);
}